// Round 5
// baseline (82.398 us; speedup 1.0000x reference)
//
#include <hip/hip_runtime.h>
#include <hip/hip_bf16.h>

#define D 8192
#define NPAIR 523776.0

typedef short short8 __attribute__((ext_vector_type(8)));
typedef float f32x4 __attribute__((ext_vector_type(4)));

__device__ __forceinline__ short8 cvt8(const float4 a, const float4 b) {
    union { short8 s; __hip_bfloat162 h[4]; } u;
    u.h[0] = __float22bfloat162_rn(make_float2(a.x, a.y));
    u.h[1] = __float22bfloat162_rn(make_float2(a.z, a.w));
    u.h[2] = __float22bfloat162_rn(make_float2(b.x, b.y));
    u.h[3] = __float22bfloat162_rn(make_float2(b.z, b.w));
    return u.s;
}

// 1024 blocks, bid = x(0..7, XCD slot) + 8*s.  m = x>>2, xr = x&3.
// DIAG FIRST (2x steps -> start at t=0 to kill the tail):
//   s < 16 : diag tiles. dt = s&7, c = (s>>3)*4 + xr (8 chunks of K=1024, 32 steps)
//   s >= 16: off-diag.  sp = s-16: c = (sp/28)*4 + xr (16 chunks of K=512, 16 steps)
__device__ __forceinline__ void decode_bid(int bid, int& m, int& ti, int& tj, int& k0, int& nsteps) {
    int x = bid & 7, s = bid >> 3;
    m = x >> 2;
    int xr = x & 3;
    if (s < 16) {
        ti = tj = s & 7;
        int c = ((s >> 3) << 2) + xr;
        k0 = c * 1024; nsteps = 32;
    } else {
        int sp = s - 16;
        int c = (sp / 28) * 4 + xr;
        int tt = sp % 28;
        int a = 0;
        while (tt >= 7 - a) { tt -= 7 - a; ++a; }
        ti = a; tj = a + 1 + tt;
        k0 = c * 512; nsteps = 16;
    }
}
__device__ __forceinline__ int bid_off(int m, int tt, int c) {
    return (m * 4 + (c & 3)) + ((16 + (c >> 2) * 28 + tt) << 3);
}
__device__ __forceinline__ int bid_diag(int m, int dt, int c) {
    return (m * 4 + (c & 3)) + ((((c >> 2) << 3) + dt) << 3);
}

template<bool STORE>
__global__ __launch_bounds__(512, 4)
void gram_kernel(const float* __restrict__ pred, const float* __restrict__ tgt,
                 float* __restrict__ out, float* __restrict__ norms) {
    int m, ti, tj, k0, nsteps;
    decode_bid(blockIdx.x, m, ti, tj, k0, nsteps);
    const bool same = (ti == tj);
    const float* __restrict__ x = m ? tgt : pred;

    __shared__ short lsA[2][4096];   // [128 rows][32 k] bf16, XOR-swizzled 16B slots
    __shared__ short lsB[2][4096];

    const int tid = threadIdx.x;
    const int lane = tid & 63;
    const int wid = tid >> 6;
    const int wr = wid >> 2, wc = wid & 3;   // 8 waves: 2x4 grid of 64x32 wave tiles

    // staging: one 8-float slot per thread per matrix: row = tid>>2, k-slot = tid&3
    const int srow = tid >> 2, sc8 = tid & 3;
    const float* __restrict__ gA = x + (size_t)(ti * 128 + srow) * D + k0 + sc8 * 8;
    const float* __restrict__ gB = x + (size_t)(tj * 128 + srow) * D + k0 + sc8 * 8;
    const int wby = srow * 64 + ((sc8 ^ ((srow >> 1) & 3)) << 4);  // swizzled LDS byte offset

    // fragment read offsets (swizzle-consistent: 16/64-row strides don't touch (row>>1)&3)
    const int rbA = (wr * 64 + (lane & 15)) * 64;
    const int rbB = (wc * 32 + (lane & 15)) * 64;
    const int kby = (((lane >> 4) ^ (((lane & 15) >> 1) & 3)) << 4);

    f32x4 zero = {0.f, 0.f, 0.f, 0.f};
    f32x4 acc[4][2];
#pragma unroll
    for (int mi = 0; mi < 4; ++mi) { acc[mi][0] = zero; acc[mi][1] = zero; }

    float4 ra0, ra1, rb0, rb1;
    // prologue: load step0, write buf0, load step1
    { const float4* p = (const float4*)gA; ra0 = p[0]; ra1 = p[1];
      if (!same) { const float4* q = (const float4*)gB; rb0 = q[0]; rb1 = q[1]; } }
    *(short8*)((char*)lsA[0] + wby) = cvt8(ra0, ra1);
    if (!same) *(short8*)((char*)lsB[0] + wby) = cvt8(rb0, rb1);
    { const float4* p = (const float4*)(gA + 32); ra0 = p[0]; ra1 = p[1];
      if (!same) { const float4* q = (const float4*)(gB + 32); rb0 = q[0]; rb1 = q[1]; } }
    asm volatile("s_waitcnt lgkmcnt(0)" ::: "memory");
    __builtin_amdgcn_s_barrier();

    for (int step = 0; step < nsteps; ++step) {
        const int cur = step & 1;
        const short* __restrict__ bufA = lsA[cur];
        const short* __restrict__ bufB = same ? lsA[cur] : lsB[cur];

        // compute first (depends only on the barrier), stage-write late (T14)
        __builtin_amdgcn_s_setprio(1);
        short8 bf0 = *(const short8*)((const char*)bufB + (rbB + kby));
        short8 bf1 = *(const short8*)((const char*)bufB + (rbB + 1024 + kby));
#pragma unroll
        for (int mi = 0; mi < 4; ++mi) {
            short8 af = *(const short8*)((const char*)bufA + (rbA + mi * 1024 + kby));
            acc[mi][0] = __builtin_amdgcn_mfma_f32_16x16x32_bf16(af, bf0, acc[mi][0], 0, 0, 0);
            acc[mi][1] = __builtin_amdgcn_mfma_f32_16x16x32_bf16(af, bf1, acc[mi][1], 0, 0, 0);
        }
        __builtin_amdgcn_s_setprio(0);

        if (step + 1 < nsteps) {
            const int nxt = cur ^ 1;
            *(short8*)((char*)lsA[nxt] + wby) = cvt8(ra0, ra1);
            if (!same) *(short8*)((char*)lsB[nxt] + wby) = cvt8(rb0, rb1);
            if (step + 2 < nsteps) {   // prefetch; stays in flight across the barrier
                const float4* p = (const float4*)(gA + (step + 2) * 32);
                ra0 = p[0]; ra1 = p[1];
                if (!same) { const float4* q = (const float4*)(gB + (step + 2) * 32); rb0 = q[0]; rb1 = q[1]; }
            }
        }
        asm volatile("s_waitcnt lgkmcnt(0)" ::: "memory");
        __builtin_amdgcn_s_barrier();
    }

    if (STORE) {
        float* __restrict__ dst = out + (size_t)blockIdx.x * 16384;
#pragma unroll
        for (int mi = 0; mi < 4; ++mi)
#pragma unroll
            for (int ni = 0; ni < 2; ++ni)
#pragma unroll
                for (int r = 0; r < 4; ++r) {
                    int li = wr * 64 + mi * 16 + (lane >> 4) * 4 + r;
                    int lj = wc * 32 + ni * 16 + (lane & 15);
                    dst[li * 128 + lj] = acc[mi][ni][r];
                    // norms from diag-tile diagonals (norms buffer zeroed by memsetAsync)
                    if (same && li == lj)
                        atomicAdd(&norms[m * 1024 + ti * 128 + li], acc[mi][ni][r]);
                }
    } else {
        float* __restrict__ g = out + (size_t)m * (1024 * 1024);
#pragma unroll
        for (int mi = 0; mi < 4; ++mi)
#pragma unroll
            for (int ni = 0; ni < 2; ++ni)
#pragma unroll
                for (int r = 0; r < 4; ++r) {
                    int gi = ti * 128 + wr * 64 + mi * 16 + (lane >> 4) * 4 + r;
                    int gj = tj * 128 + wc * 32 + ni * 16 + (lane & 15);
                    atomicAdd(&g[gi * 1024 + gj], acc[mi][ni][r]);
                }
    }
}

// store path: each thread handles 4 consecutive j for one i (float4 gathers),
// per-block partial store; LAST block (atomic ticket) reduces all partials -> out.
__global__ __launch_bounds__(256)
void loss_store_kernel(const float* __restrict__ part, const float* __restrict__ norms,
                       float* __restrict__ partial, unsigned int* __restrict__ ticket,
                       float* __restrict__ out) {
    const int tid = threadIdx.x;
    const int qid = blockIdx.x * 256 + tid;     // 0..262143
    const int i = qid >> 8;
    const int j0 = (qid & 255) << 2;
    float local = 0.f;
    const int ti = i >> 7, tj = j0 >> 7;
    if (tj > ti || (tj == ti && j0 + 3 > i)) {
        const int el = ((i & 127) << 7) + (j0 & 127);
        f32x4 gp = {0.f, 0.f, 0.f, 0.f}, gt = {0.f, 0.f, 0.f, 0.f};
        if (ti == tj) {
#pragma unroll
            for (int c = 0; c < 8; ++c) {
                gp += *(const f32x4*)&part[(size_t)bid_diag(0, ti, c) * 16384 + el];
                gt += *(const f32x4*)&part[(size_t)bid_diag(1, ti, c) * 16384 + el];
            }
        } else {
            int tt = 7 * ti - (ti * (ti - 1)) / 2 + (tj - ti - 1);
#pragma unroll
            for (int c = 0; c < 16; ++c) {
                gp += *(const f32x4*)&part[(size_t)bid_off(0, tt, c) * 16384 + el];
                gt += *(const f32x4*)&part[(size_t)bid_off(1, tt, c) * 16384 + el];
            }
        }
        const float nip = norms[i], nit = norms[1024 + i];
#pragma unroll
        for (int e = 0; e < 4; ++e) {
            int j = j0 + e;
            if (j > i) {
                float dp = nip + norms[j] - 2.f * gp[e];
                float dt = nit + norms[1024 + j] - 2.f * gt[e];
                float c2 = sqrtf(fmaxf(dp, 0.f)) - sqrtf(fmaxf(dt, 0.f));
                local += c2 * c2;
            }
        }
    }
#pragma unroll
    for (int off = 32; off > 0; off >>= 1) local += __shfl_down(local, off);
    __shared__ float wsum[4];
    if ((tid & 63) == 0) wsum[tid >> 6] = local;
    __syncthreads();
    __shared__ unsigned int slast;
    if (tid == 0) {
        partial[blockIdx.x] = wsum[0] + wsum[1] + wsum[2] + wsum[3];
        __threadfence();                       // release: partial visible before ticket
        slast = atomicAdd(ticket, 1u);
    }
    __syncthreads();
    if (slast == 1023u) {                      // last block reduces (order-independent)
        __threadfence();                       // acquire: see all partials
        double lsum = 0.0;
#pragma unroll
        for (int k = 0; k < 4; ++k) lsum += (double)partial[tid + k * 256];
#pragma unroll
        for (int off = 32; off > 0; off >>= 1) lsum += __shfl_down(lsum, off);
        __shared__ double dsum[4];
        if ((tid & 63) == 0) dsum[tid >> 6] = lsum;
        __syncthreads();
        if (tid == 0) out[0] = (float)((dsum[0] + dsum[1] + dsum[2] + dsum[3]) / NPAIR);
    }
}

// fallback loss (atomic gram path): reads dense gram[2][1024][1024]
__global__ __launch_bounds__(256)
void loss_atomic_kernel(const float* __restrict__ gram, float* __restrict__ partial,
                        unsigned int* __restrict__ ticket, float* __restrict__ out) {
    const float* __restrict__ gP = gram;
    const float* __restrict__ gT = gram + 1024 * 1024;
    const int tid = threadIdx.x;
    const int base = blockIdx.x * 256 + tid;
    float local = 0.f;
#pragma unroll
    for (int s = 0; s < 4; ++s) {
        int lin = base + s * 262144;
        int i = lin >> 10, j = lin & 1023;
        if (j > i) {
            float dp = gP[i * 1024 + i] + gP[j * 1024 + j] - 2.f * gP[lin];
            float dt = gT[i * 1024 + i] + gT[j * 1024 + j] - 2.f * gT[lin];
            float c = sqrtf(fmaxf(dp, 0.f)) - sqrtf(fmaxf(dt, 0.f));
            local += c * c;
        }
    }
#pragma unroll
    for (int off = 32; off > 0; off >>= 1) local += __shfl_down(local, off);
    __shared__ float wsum[4];
    if ((tid & 63) == 0) wsum[tid >> 6] = local;
    __syncthreads();
    __shared__ unsigned int slast;
    if (tid == 0) {
        partial[blockIdx.x] = wsum[0] + wsum[1] + wsum[2] + wsum[3];
        __threadfence();
        slast = atomicAdd(ticket, 1u);
    }
    __syncthreads();
    if (slast == 1023u) {
        __threadfence();
        double lsum = 0.0;
#pragma unroll
        for (int k = 0; k < 4; ++k) lsum += (double)partial[tid + k * 256];
#pragma unroll
        for (int off = 32; off > 0; off >>= 1) lsum += __shfl_down(lsum, off);
        __shared__ double dsum[4];
        if ((tid & 63) == 0) dsum[tid >> 6] = lsum;
        __syncthreads();
        if (tid == 0) out[0] = (float)((dsum[0] + dsum[1] + dsum[2] + dsum[3]) / NPAIR);
    }
}

extern "C" void kernel_launch(void* const* d_in, const int* in_sizes, int n_in,
                              void* d_out, int out_size, void* d_ws, size_t ws_size,
                              hipStream_t stream) {
    const float* pred = (const float*)d_in[0];
    const float* tgt  = (const float*)d_in[1];
    float* ws = (float*)d_ws;
    // layout: part[1024*16384] | norms[2048] | ticket[1] | partial[1024]
    const size_t need = ((size_t)1024 * 16384 + 2048 + 1 + 1024) * 4;
    if (ws_size >= need) {
        float* part    = ws;
        float* norms   = ws + (size_t)1024 * 16384;
        unsigned int* ticket = (unsigned int*)(norms + 2048);
        float* partial = norms + 2049;
        hipMemsetAsync(norms, 0, 2049 * sizeof(float), stream);   // norms + ticket
        gram_kernel<true><<<1024, 512, 0, stream>>>(pred, tgt, part, norms);
        loss_store_kernel<<<1024, 256, 0, stream>>>(part, norms, partial, ticket, (float*)d_out);
    } else {
        float* gram = ws;                            // 2 x 1024 x 1024 f32 = 8 MB
        unsigned int* ticket = (unsigned int*)(ws + (size_t)2 * 1024 * 1024);
        float* partial = ws + (size_t)2 * 1024 * 1024 + 1;
        hipMemsetAsync(gram, 0, ((size_t)2 * 1024 * 1024 + 1) * sizeof(float), stream);
        gram_kernel<false><<<1024, 512, 0, stream>>>(pred, tgt, gram, nullptr);
        loss_atomic_kernel<<<1024, 256, 0, stream>>>(gram, partial, ticket, (float*)d_out);
    }
}

// Round 6
// 68.338 us; speedup vs baseline: 1.2057x; 1.2057x over previous
//
#include <hip/hip_runtime.h>
#include <hip/hip_bf16.h>

#define D 8192
#define NPAIR 523776.0

typedef short short8 __attribute__((ext_vector_type(8)));
typedef float f32x4 __attribute__((ext_vector_type(4)));

__device__ __forceinline__ short8 cvt8(const float4 a, const float4 b) {
    union { short8 s; __hip_bfloat162 h[4]; } u;
    u.h[0] = __float22bfloat162_rn(make_float2(a.x, a.y));
    u.h[1] = __float22bfloat162_rn(make_float2(a.z, a.w));
    u.h[2] = __float22bfloat162_rn(make_float2(b.x, b.y));
    u.h[3] = __float22bfloat162_rn(make_float2(b.z, b.w));
    return u.s;
}

// 1024 blocks, bid = x(0..7, XCD slot) + 8*s.  m = x>>2, xr = x&3.
// DIAG FIRST (2x steps -> start at t=0 to kill the tail):
//   s < 16 : diag tiles. dt = s&7, c = (s>>3)*4 + xr (8 chunks of K=1024, 16 steps @ BK=64)
//   s >= 16: off-diag.  sp = s-16: c = (sp/28)*4 + xr (16 chunks of K=512, 8 steps @ BK=64)
__device__ __forceinline__ void decode_bid(int bid, int& m, int& ti, int& tj, int& k0, int& nsteps) {
    int x = bid & 7, s = bid >> 3;
    m = x >> 2;
    int xr = x & 3;
    if (s < 16) {
        ti = tj = s & 7;
        int c = ((s >> 3) << 2) + xr;
        k0 = c * 1024; nsteps = 16;
    } else {
        int sp = s - 16;
        int c = (sp / 28) * 4 + xr;
        int tt = sp % 28;
        int a = 0;
        while (tt >= 7 - a) { tt -= 7 - a; ++a; }
        ti = a; tj = a + 1 + tt;
        k0 = c * 512; nsteps = 8;
    }
}
__device__ __forceinline__ int bid_off(int m, int tt, int c) {
    return (m * 4 + (c & 3)) + ((16 + (c >> 2) * 28 + tt) << 3);
}
__device__ __forceinline__ int bid_diag(int m, int dt, int c) {
    return (m * 4 + (c & 3)) + ((((c >> 2) << 3) + dt) << 3);
}

template<bool STORE>
__global__ __launch_bounds__(512, 4)
void gram_kernel(const float* __restrict__ pred, const float* __restrict__ tgt,
                 float* __restrict__ out, float* __restrict__ norms) {
    int m, ti, tj, k0, nsteps;
    decode_bid(blockIdx.x, m, ti, tj, k0, nsteps);
    const bool same = (ti == tj);
    const float* __restrict__ x = m ? tgt : pred;

    __shared__ short lsA[2][8192];   // [2 buf][128 rows][64 k] bf16, XOR-swizzled 16B slots
    __shared__ short lsB[2][8192];

    const int tid = threadIdx.x;
    const int lane = tid & 63;
    const int wid = tid >> 6;
    const int wr = wid >> 2, wc = wid & 3;   // 8 waves: 2x4 grid of 64x32 wave tiles

    // staging: row = tid>>2 (0..127), st = tid&3 -> 16 consecutive floats at k = st*16
    const int srow = tid >> 2, st = tid & 3;
    const float* __restrict__ gA = x + (size_t)(ti * 128 + srow) * D + k0 + st * 16;
    const float* __restrict__ gB = x + (size_t)(tj * 128 + srow) * D + k0 + st * 16;
    const int sw = (srow >> 1) & 3;          // XOR on 16B-slot index (slots 0..7 per 128B row)
    const int wby0 = srow * 128 + ((((st << 1))     ^ sw) << 4);
    const int wby1 = srow * 128 + ((((st << 1) | 1) ^ sw) << 4);

    // fragment read offsets (row stride 128B); slot = (lane>>4)+4h, XOR by frag-row bits
    const int rbA = (wr * 64 + (lane & 15)) * 128;
    const int rbB = (wc * 32 + (lane & 15)) * 128;
    const int kXor = ((lane & 15) >> 1) & 3;
    const int kby0 = (((lane >> 4)    ) ^ kXor) << 4;
    const int kby1 = (((lane >> 4) + 4) ^ kXor) << 4;   // +4 is bit2, XOR hits bits0-1: safe

    f32x4 zero = {0.f, 0.f, 0.f, 0.f};
    f32x4 acc[4][2];
#pragma unroll
    for (int mi = 0; mi < 4; ++mi) { acc[mi][0] = zero; acc[mi][1] = zero; }

    float4 ra[4], rb[4];
    // prologue: load step0, write buf0, load step1
    {
        const float4* p = (const float4*)gA;
#pragma unroll
        for (int q = 0; q < 4; ++q) ra[q] = p[q];
        if (!same) {
            const float4* r = (const float4*)gB;
#pragma unroll
            for (int q = 0; q < 4; ++q) rb[q] = r[q];
        }
    }
    *(short8*)((char*)lsA[0] + wby0) = cvt8(ra[0], ra[1]);
    *(short8*)((char*)lsA[0] + wby1) = cvt8(ra[2], ra[3]);
    if (!same) {
        *(short8*)((char*)lsB[0] + wby0) = cvt8(rb[0], rb[1]);
        *(short8*)((char*)lsB[0] + wby1) = cvt8(rb[2], rb[3]);
    }
    {
        const float4* p = (const float4*)(gA + 64);
#pragma unroll
        for (int q = 0; q < 4; ++q) ra[q] = p[q];
        if (!same) {
            const float4* r = (const float4*)(gB + 64);
#pragma unroll
            for (int q = 0; q < 4; ++q) rb[q] = r[q];
        }
    }
    asm volatile("s_waitcnt lgkmcnt(0)" ::: "memory");
    __builtin_amdgcn_s_barrier();

    for (int step = 0; step < nsteps; ++step) {
        const int cur = step & 1;
        const short* __restrict__ bufA = lsA[cur];
        const short* __restrict__ bufB = same ? lsA[cur] : lsB[cur];

        // compute first (depends only on the barrier), stage-write late (T14)
        __builtin_amdgcn_s_setprio(1);
#pragma unroll
        for (int h = 0; h < 2; ++h) {
            const int kby = h ? kby1 : kby0;
            short8 bf0 = *(const short8*)((const char*)bufB + (rbB + kby));
            short8 bf1 = *(const short8*)((const char*)bufB + (rbB + 2048 + kby));
#pragma unroll
            for (int mi = 0; mi < 4; ++mi) {
                short8 af = *(const short8*)((const char*)bufA + (rbA + mi * 2048 + kby));
                acc[mi][0] = __builtin_amdgcn_mfma_f32_16x16x32_bf16(af, bf0, acc[mi][0], 0, 0, 0);
                acc[mi][1] = __builtin_amdgcn_mfma_f32_16x16x32_bf16(af, bf1, acc[mi][1], 0, 0, 0);
            }
        }
        __builtin_amdgcn_s_setprio(0);

        if (step + 1 < nsteps) {
            const int nxt = cur ^ 1;
            *(short8*)((char*)lsA[nxt] + wby0) = cvt8(ra[0], ra[1]);
            *(short8*)((char*)lsA[nxt] + wby1) = cvt8(ra[2], ra[3]);
            if (!same) {
                *(short8*)((char*)lsB[nxt] + wby0) = cvt8(rb[0], rb[1]);
                *(short8*)((char*)lsB[nxt] + wby1) = cvt8(rb[2], rb[3]);
            }
            if (step + 2 < nsteps) {   // prefetch; stays in flight across the barrier
                const float4* p = (const float4*)(gA + (step + 2) * 64);
#pragma unroll
                for (int q = 0; q < 4; ++q) ra[q] = p[q];
                if (!same) {
                    const float4* r = (const float4*)(gB + (step + 2) * 64);
#pragma unroll
                    for (int q = 0; q < 4; ++q) rb[q] = r[q];
                }
            }
        }
        asm volatile("s_waitcnt lgkmcnt(0)" ::: "memory");
        __builtin_amdgcn_s_barrier();
    }

    if (STORE) {
        float* __restrict__ dst = out + (size_t)blockIdx.x * 16384;
#pragma unroll
        for (int mi = 0; mi < 4; ++mi)
#pragma unroll
            for (int ni = 0; ni < 2; ++ni)
#pragma unroll
                for (int r = 0; r < 4; ++r) {
                    int li = wr * 64 + mi * 16 + (lane >> 4) * 4 + r;
                    int lj = wc * 32 + ni * 16 + (lane & 15);
                    dst[li * 128 + lj] = acc[mi][ni][r];
                    // norms from diag-tile diagonals (norms buffer zeroed by memsetAsync)
                    if (same && li == lj)
                        atomicAdd(&norms[m * 1024 + ti * 128 + li], acc[mi][ni][r]);
                }
    } else {
        float* __restrict__ g = out + (size_t)m * (1024 * 1024);
#pragma unroll
        for (int mi = 0; mi < 4; ++mi)
#pragma unroll
            for (int ni = 0; ni < 2; ++ni)
#pragma unroll
                for (int r = 0; r < 4; ++r) {
                    int gi = ti * 128 + wr * 64 + mi * 16 + (lane >> 4) * 4 + r;
                    int gj = tj * 128 + wc * 32 + ni * 16 + (lane & 15);
                    atomicAdd(&g[gi * 1024 + gj], acc[mi][ni][r]);
                }
    }
}

// round-2 proven loss: lin-mapped scalar gathers (wave = 64 consecutive j of one i,
// perfectly coalesced), per-block partial store, separate tiny finalize kernel.
__global__ __launch_bounds__(256)
void loss_store_kernel(const float* __restrict__ part, const float* __restrict__ norms,
                       float* __restrict__ partial) {
    const int tid = threadIdx.x;
    const int base = blockIdx.x * 256 + tid;
    float local = 0.f;
#pragma unroll
    for (int s = 0; s < 4; ++s) {
        int lin = base + s * 262144;
        int i = lin >> 10, j = lin & 1023;
        if (j > i) {
            int ti = i >> 7, tj = j >> 7;
            int el = ((i & 127) << 7) + (j & 127);
            float gp = 0.f, gt = 0.f;
            if (ti == tj) {
#pragma unroll
                for (int c = 0; c < 8; ++c) {
                    gp += part[(size_t)bid_diag(0, ti, c) * 16384 + el];
                    gt += part[(size_t)bid_diag(1, ti, c) * 16384 + el];
                }
            } else {
                int tt = 7 * ti - (ti * (ti - 1)) / 2 + (tj - ti - 1);
#pragma unroll
                for (int c = 0; c < 16; ++c) {
                    gp += part[(size_t)bid_off(0, tt, c) * 16384 + el];
                    gt += part[(size_t)bid_off(1, tt, c) * 16384 + el];
                }
            }
            float dp = norms[i] + norms[j] - 2.f * gp;
            float dt_ = norms[1024 + i] + norms[1024 + j] - 2.f * gt;
            float c2 = sqrtf(fmaxf(dp, 0.f)) - sqrtf(fmaxf(dt_, 0.f));
            local += c2 * c2;
        }
    }
#pragma unroll
    for (int off = 32; off > 0; off >>= 1) local += __shfl_down(local, off);
    __shared__ float wsum[4];
    if ((tid & 63) == 0) wsum[tid >> 6] = local;
    __syncthreads();
    if (tid == 0) partial[blockIdx.x] = wsum[0] + wsum[1] + wsum[2] + wsum[3];
}

// fallback loss (atomic gram path): reads dense gram[2][1024][1024]
__global__ __launch_bounds__(256)
void loss_atomic_kernel(const float* __restrict__ gram, float* __restrict__ partial) {
    const float* __restrict__ gP = gram;
    const float* __restrict__ gT = gram + 1024 * 1024;
    const int tid = threadIdx.x;
    const int base = blockIdx.x * 256 + tid;
    float local = 0.f;
#pragma unroll
    for (int s = 0; s < 4; ++s) {
        int lin = base + s * 262144;
        int i = lin >> 10, j = lin & 1023;
        if (j > i) {
            float dp = gP[i * 1024 + i] + gP[j * 1024 + j] - 2.f * gP[lin];
            float dt = gT[i * 1024 + i] + gT[j * 1024 + j] - 2.f * gT[lin];
            float c = sqrtf(fmaxf(dp, 0.f)) - sqrtf(fmaxf(dt, 0.f));
            local += c * c;
        }
    }
#pragma unroll
    for (int off = 32; off > 0; off >>= 1) local += __shfl_down(local, off);
    __shared__ float wsum[4];
    if ((tid & 63) == 0) wsum[tid >> 6] = local;
    __syncthreads();
    if (tid == 0) partial[blockIdx.x] = wsum[0] + wsum[1] + wsum[2] + wsum[3];
}

__global__ __launch_bounds__(256)
void finalize_kernel(const float* __restrict__ partial, float* __restrict__ out) {
    const int tid = threadIdx.x;
    double local = 0.0;
#pragma unroll
    for (int k = 0; k < 4; ++k) local += (double)partial[tid + k * 256];
#pragma unroll
    for (int off = 32; off > 0; off >>= 1) local += __shfl_down(local, off);
    __shared__ double wsum[4];
    if ((tid & 63) == 0) wsum[tid >> 6] = local;
    __syncthreads();
    if (tid == 0) out[0] = (float)((wsum[0] + wsum[1] + wsum[2] + wsum[3]) / NPAIR);
}

extern "C" void kernel_launch(void* const* d_in, const int* in_sizes, int n_in,
                              void* d_out, int out_size, void* d_ws, size_t ws_size,
                              hipStream_t stream) {
    const float* pred = (const float*)d_in[0];
    const float* tgt  = (const float*)d_in[1];
    float* ws = (float*)d_ws;
    // layout: part[1024*16384] | norms[2048] | partial[1024]
    const size_t need = ((size_t)1024 * 16384 + 2048 + 1024) * 4;
    if (ws_size >= need) {
        float* part    = ws;
        float* norms   = ws + (size_t)1024 * 16384;
        float* partial = norms + 2048;
        hipMemsetAsync(norms, 0, 2048 * sizeof(float), stream);
        gram_kernel<true><<<1024, 512, 0, stream>>>(pred, tgt, part, norms);
        loss_store_kernel<<<1024, 256, 0, stream>>>(part, norms, partial);
        finalize_kernel<<<1, 256, 0, stream>>>(partial, (float*)d_out);
    } else {
        float* gram    = ws;                            // 2 x 1024 x 1024 f32 = 8 MB
        float* partial = ws + (size_t)2 * 1024 * 1024;
        hipMemsetAsync(gram, 0, (size_t)2 * 1024 * 1024 * sizeof(float), stream);
        gram_kernel<false><<<1024, 512, 0, stream>>>(pred, tgt, gram, nullptr);
        loss_atomic_kernel<<<1024, 256, 0, stream>>>(gram, partial);
        finalize_kernel<<<1, 256, 0, stream>>>(partial, (float*)d_out);
    }
}

// Round 7
// 63.596 us; speedup vs baseline: 1.2956x; 1.0746x over previous
//
#include <hip/hip_runtime.h>
#include <hip/hip_bf16.h>

#define D 8192
#define NPAIR 523776.0

typedef short short8 __attribute__((ext_vector_type(8)));
typedef float f32x4 __attribute__((ext_vector_type(4)));

__device__ __forceinline__ short8 cvt8(const float4 a, const float4 b) {
    union { short8 s; __hip_bfloat162 h[4]; } u;
    u.h[0] = __float22bfloat162_rn(make_float2(a.x, a.y));
    u.h[1] = __float22bfloat162_rn(make_float2(a.z, a.w));
    u.h[2] = __float22bfloat162_rn(make_float2(b.x, b.y));
    u.h[3] = __float22bfloat162_rn(make_float2(b.z, b.w));
    return u.s;
}

// 1024 blocks, bid = x(0..7, XCD slot) + 8*s.  m = x>>2, xr = x&3.
// DIAG FIRST (2x steps -> start at t=0 to kill the tail):
//   s < 16 : diag tiles. dt = s&7, c = (s>>3)*4 + xr (8 chunks of K=1024, 32 steps @ BK=32)
//   s >= 16: off-diag.  sp = s-16: c = (sp/28)*4 + xr (16 chunks of K=512, 16 steps @ BK=32)
__device__ __forceinline__ void decode_bid(int bid, int& m, int& ti, int& tj, int& k0, int& nsteps) {
    int x = bid & 7, s = bid >> 3;
    m = x >> 2;
    int xr = x & 3;
    if (s < 16) {
        ti = tj = s & 7;
        int c = ((s >> 3) << 2) + xr;
        k0 = c * 1024; nsteps = 32;
    } else {
        int sp = s - 16;
        int c = (sp / 28) * 4 + xr;
        int tt = sp % 28;
        int a = 0;
        while (tt >= 7 - a) { tt -= 7 - a; ++a; }
        ti = a; tj = a + 1 + tt;
        k0 = c * 512; nsteps = 16;
    }
}
__device__ __forceinline__ int bid_off(int m, int tt, int c) {
    return (m * 4 + (c & 3)) + ((16 + (c >> 2) * 28 + tt) << 3);
}
__device__ __forceinline__ int bid_diag(int m, int dt, int c) {
    return (m * 4 + (c & 3)) + ((((c >> 2) << 3) + dt) << 3);
}

template<bool STORE>
__global__ __launch_bounds__(512, 4)
void gram_kernel(const float* __restrict__ pred, const float* __restrict__ tgt,
                 float* __restrict__ out, float* __restrict__ norms) {
    int m, ti, tj, k0, nsteps;
    decode_bid(blockIdx.x, m, ti, tj, k0, nsteps);
    const bool same = (ti == tj);
    const float* __restrict__ x = m ? tgt : pred;

    __shared__ short lsA[2][4096];   // [128 rows][32 k] bf16, XOR-swizzled 16B slots
    __shared__ short lsB[2][4096];

    const int tid = threadIdx.x;
    const int lane = tid & 63;
    const int wid = tid >> 6;
    const int wr = wid >> 2, wc = wid & 3;   // 8 waves: 2x4 grid of 64x32 wave tiles

    // staging: one 8-float slot per thread per matrix: row = tid>>2, k-slot = tid&3
    const int srow = tid >> 2, sc8 = tid & 3;
    const float* __restrict__ gA = x + (size_t)(ti * 128 + srow) * D + k0 + sc8 * 8;
    const float* __restrict__ gB = x + (size_t)(tj * 128 + srow) * D + k0 + sc8 * 8;
    const int wby = srow * 64 + ((sc8 ^ ((srow >> 1) & 3)) << 4);  // swizzled LDS byte offset

    // fragment read offsets (swizzle-consistent: 16/64-row strides don't touch (row>>1)&3)
    const int rbA = (wr * 64 + (lane & 15)) * 64;
    const int rbB = (wc * 32 + (lane & 15)) * 64;
    const int kby = (((lane >> 4) ^ (((lane & 15) >> 1) & 3)) << 4);

    f32x4 zero = {0.f, 0.f, 0.f, 0.f};
    f32x4 acc[4][2];
#pragma unroll
    for (int mi = 0; mi < 4; ++mi) { acc[mi][0] = zero; acc[mi][1] = zero; }

    float4 ra0, ra1, rb0, rb1;
    // prologue: load step0, write buf0, load step1
    { const float4* p = (const float4*)gA; ra0 = p[0]; ra1 = p[1];
      if (!same) { const float4* q = (const float4*)gB; rb0 = q[0]; rb1 = q[1]; } }
    *(short8*)((char*)lsA[0] + wby) = cvt8(ra0, ra1);
    if (!same) *(short8*)((char*)lsB[0] + wby) = cvt8(rb0, rb1);
    { const float4* p = (const float4*)(gA + 32); ra0 = p[0]; ra1 = p[1];
      if (!same) { const float4* q = (const float4*)(gB + 32); rb0 = q[0]; rb1 = q[1]; } }
    asm volatile("s_waitcnt lgkmcnt(0)" ::: "memory");
    __builtin_amdgcn_s_barrier();

    for (int step = 0; step < nsteps; ++step) {
        const int cur = step & 1;
        const short* __restrict__ bufA = lsA[cur];
        const short* __restrict__ bufB = same ? lsA[cur] : lsB[cur];

        // compute first (depends only on the barrier), stage-write late (T14)
        __builtin_amdgcn_s_setprio(1);
        short8 bf0 = *(const short8*)((const char*)bufB + (rbB + kby));
        short8 bf1 = *(const short8*)((const char*)bufB + (rbB + 1024 + kby));
#pragma unroll
        for (int mi = 0; mi < 4; ++mi) {
            short8 af = *(const short8*)((const char*)bufA + (rbA + mi * 1024 + kby));
            acc[mi][0] = __builtin_amdgcn_mfma_f32_16x16x32_bf16(af, bf0, acc[mi][0], 0, 0, 0);
            acc[mi][1] = __builtin_amdgcn_mfma_f32_16x16x32_bf16(af, bf1, acc[mi][1], 0, 0, 0);
        }
        __builtin_amdgcn_s_setprio(0);

        if (step + 1 < nsteps) {
            const int nxt = cur ^ 1;
            *(short8*)((char*)lsA[nxt] + wby) = cvt8(ra0, ra1);
            if (!same) *(short8*)((char*)lsB[nxt] + wby) = cvt8(rb0, rb1);
            if (step + 2 < nsteps) {   // prefetch; stays in flight across the barrier
                const float4* p = (const float4*)(gA + (step + 2) * 32);
                ra0 = p[0]; ra1 = p[1];
                if (!same) { const float4* q = (const float4*)(gB + (step + 2) * 32); rb0 = q[0]; rb1 = q[1]; }
            }
        }
        asm volatile("s_waitcnt lgkmcnt(0)" ::: "memory");
        __builtin_amdgcn_s_barrier();
    }

    if (STORE) {
        float* __restrict__ dst = out + (size_t)blockIdx.x * 16384;
#pragma unroll
        for (int mi = 0; mi < 4; ++mi)
#pragma unroll
            for (int ni = 0; ni < 2; ++ni)
#pragma unroll
                for (int r = 0; r < 4; ++r) {
                    int li = wr * 64 + mi * 16 + (lane >> 4) * 4 + r;
                    int lj = wc * 32 + ni * 16 + (lane & 15);
                    dst[li * 128 + lj] = acc[mi][ni][r];
                    // norms from diag-tile diagonals (norms buffer zeroed by memsetAsync)
                    if (same && li == lj)
                        atomicAdd(&norms[m * 1024 + ti * 128 + li], acc[mi][ni][r]);
                }
    } else {
        float* __restrict__ g = out + (size_t)m * (1024 * 1024);
#pragma unroll
        for (int mi = 0; mi < 4; ++mi)
#pragma unroll
            for (int ni = 0; ni < 2; ++ni)
#pragma unroll
                for (int r = 0; r < 4; ++r) {
                    int gi = ti * 128 + wr * 64 + mi * 16 + (lane >> 4) * 4 + r;
                    int gj = tj * 128 + wc * 32 + ni * 16 + (lane & 15);
                    atomicAdd(&g[gi * 1024 + gj], acc[mi][ni][r]);
                }
    }
}

// loss: wave = 64 consecutive j of one i (coalesced scalar gathers),
// per-block partial store, separate tiny finalize kernel (no fences, no same-addr atomics).
__global__ __launch_bounds__(256)
void loss_store_kernel(const float* __restrict__ part, const float* __restrict__ norms,
                       float* __restrict__ partial) {
    const int tid = threadIdx.x;
    const int base = blockIdx.x * 256 + tid;
    float local = 0.f;
#pragma unroll
    for (int s = 0; s < 4; ++s) {
        int lin = base + s * 262144;
        int i = lin >> 10, j = lin & 1023;
        if (j > i) {
            int ti = i >> 7, tj = j >> 7;
            int el = ((i & 127) << 7) + (j & 127);
            float gp = 0.f, gt = 0.f;
            if (ti == tj) {
#pragma unroll
                for (int c = 0; c < 8; ++c) {
                    gp += part[(size_t)bid_diag(0, ti, c) * 16384 + el];
                    gt += part[(size_t)bid_diag(1, ti, c) * 16384 + el];
                }
            } else {
                int tt = 7 * ti - (ti * (ti - 1)) / 2 + (tj - ti - 1);
#pragma unroll
                for (int c = 0; c < 16; ++c) {
                    gp += part[(size_t)bid_off(0, tt, c) * 16384 + el];
                    gt += part[(size_t)bid_off(1, tt, c) * 16384 + el];
                }
            }
            float dp = norms[i] + norms[j] - 2.f * gp;
            float dt_ = norms[1024 + i] + norms[1024 + j] - 2.f * gt;
            float c2 = sqrtf(fmaxf(dp, 0.f)) - sqrtf(fmaxf(dt_, 0.f));
            local += c2 * c2;
        }
    }
#pragma unroll
    for (int off = 32; off > 0; off >>= 1) local += __shfl_down(local, off);
    __shared__ float wsum[4];
    if ((tid & 63) == 0) wsum[tid >> 6] = local;
    __syncthreads();
    if (tid == 0) partial[blockIdx.x] = wsum[0] + wsum[1] + wsum[2] + wsum[3];
}

// fallback loss (atomic gram path): reads dense gram[2][1024][1024]
__global__ __launch_bounds__(256)
void loss_atomic_kernel(const float* __restrict__ gram, float* __restrict__ partial) {
    const float* __restrict__ gP = gram;
    const float* __restrict__ gT = gram + 1024 * 1024;
    const int tid = threadIdx.x;
    const int base = blockIdx.x * 256 + tid;
    float local = 0.f;
#pragma unroll
    for (int s = 0; s < 4; ++s) {
        int lin = base + s * 262144;
        int i = lin >> 10, j = lin & 1023;
        if (j > i) {
            float dp = gP[i * 1024 + i] + gP[j * 1024 + j] - 2.f * gP[lin];
            float dt = gT[i * 1024 + i] + gT[j * 1024 + j] - 2.f * gT[lin];
            float c = sqrtf(fmaxf(dp, 0.f)) - sqrtf(fmaxf(dt, 0.f));
            local += c * c;
        }
    }
#pragma unroll
    for (int off = 32; off > 0; off >>= 1) local += __shfl_down(local, off);
    __shared__ float wsum[4];
    if ((tid & 63) == 0) wsum[tid >> 6] = local;
    __syncthreads();
    if (tid == 0) partial[blockIdx.x] = wsum[0] + wsum[1] + wsum[2] + wsum[3];
}

__global__ __launch_bounds__(256)
void finalize_kernel(const float* __restrict__ partial, float* __restrict__ out) {
    const int tid = threadIdx.x;
    double local = 0.0;
#pragma unroll
    for (int k = 0; k < 4; ++k) local += (double)partial[tid + k * 256];
#pragma unroll
    for (int off = 32; off > 0; off >>= 1) local += __shfl_down(local, off);
    __shared__ double wsum[4];
    if ((tid & 63) == 0) wsum[tid >> 6] = local;
    __syncthreads();
    if (tid == 0) out[0] = (float)((wsum[0] + wsum[1] + wsum[2] + wsum[3]) / NPAIR);
}

extern "C" void kernel_launch(void* const* d_in, const int* in_sizes, int n_in,
                              void* d_out, int out_size, void* d_ws, size_t ws_size,
                              hipStream_t stream) {
    const float* pred = (const float*)d_in[0];
    const float* tgt  = (const float*)d_in[1];
    float* ws = (float*)d_ws;
    // layout: part[1024*16384] | norms[2048] | partial[1024]
    const size_t need = ((size_t)1024 * 16384 + 2048 + 1024) * 4;
    if (ws_size >= need) {
        float* part    = ws;
        float* norms   = ws + (size_t)1024 * 16384;
        float* partial = norms + 2048;
        hipMemsetAsync(norms, 0, 2048 * sizeof(float), stream);
        gram_kernel<true><<<1024, 512, 0, stream>>>(pred, tgt, part, norms);
        loss_store_kernel<<<1024, 256, 0, stream>>>(part, norms, partial);
        finalize_kernel<<<1, 256, 0, stream>>>(partial, (float*)d_out);
    } else {
        float* gram    = ws;                            // 2 x 1024 x 1024 f32 = 8 MB
        float* partial = ws + (size_t)2 * 1024 * 1024;
        hipMemsetAsync(gram, 0, (size_t)2 * 1024 * 1024 * sizeof(float), stream);
        gram_kernel<false><<<1024, 512, 0, stream>>>(pred, tgt, gram, nullptr);
        loss_atomic_kernel<<<1024, 256, 0, stream>>>(gram, partial);
        finalize_kernel<<<1, 256, 0, stream>>>(partial, (float*)d_out);
    }
}

// Round 8
// 62.451 us; speedup vs baseline: 1.3194x; 1.0183x over previous
//
#include <hip/hip_runtime.h>
#include <hip/hip_bf16.h>

#define D 8192
#define NPAIR 523776.0

typedef short short8 __attribute__((ext_vector_type(8)));
typedef float f32x4 __attribute__((ext_vector_type(4)));

__device__ __forceinline__ short8 cvt8(const float4 a, const float4 b) {
    union { short8 s; __hip_bfloat162 h[4]; } u;
    u.h[0] = __float22bfloat162_rn(make_float2(a.x, a.y));
    u.h[1] = __float22bfloat162_rn(make_float2(a.z, a.w));
    u.h[2] = __float22bfloat162_rn(make_float2(b.x, b.y));
    u.h[3] = __float22bfloat162_rn(make_float2(b.z, b.w));
    return u.s;
}

// 1024 blocks, bid = x(0..7, XCD slot) + 8*s.  m = x>>2, xr = x&3.
// DIAG FIRST (2x steps -> start at t=0 to kill the tail):
//   s < 16 : diag tiles. dt = s&7, c = (s>>3)*4 + xr (8 chunks of K=1024, 32 steps @ BK=32)
//   s >= 16: off-diag.  sp = s-16: c = (sp/28)*4 + xr (16 chunks of K=512, 16 steps @ BK=32)
__device__ __forceinline__ void decode_bid(int bid, int& m, int& ti, int& tj, int& k0, int& nsteps) {
    int x = bid & 7, s = bid >> 3;
    m = x >> 2;
    int xr = x & 3;
    if (s < 16) {
        ti = tj = s & 7;
        int c = ((s >> 3) << 2) + xr;
        k0 = c * 1024; nsteps = 32;
    } else {
        int sp = s - 16;
        int c = (sp / 28) * 4 + xr;
        int tt = sp % 28;
        int a = 0;
        while (tt >= 7 - a) { tt -= 7 - a; ++a; }
        ti = a; tj = a + 1 + tt;
        k0 = c * 512; nsteps = 16;
    }
}
__device__ __forceinline__ int bid_off(int m, int tt, int c) {
    return (m * 4 + (c & 3)) + ((16 + (c >> 2) * 28 + tt) << 3);
}
__device__ __forceinline__ int bid_diag(int m, int dt, int c) {
    return (m * 4 + (c & 3)) + ((((c >> 2) << 3) + dt) << 3);
}

// one pipeline step: MFMA on lsX[S&1]; write staged regs (data for step S+1) to
// lsX[(S&1)^1]; issue loads for step S+3 into the same (now free) register set.
#define GRAM_STEP(S, RA, RB) { \
    const int cur_ = (S) & 1; \
    const short* __restrict__ bufA = lsA[cur_]; \
    const short* __restrict__ bufB = same ? lsA[cur_] : lsB[cur_]; \
    __builtin_amdgcn_s_setprio(1); \
    short8 bf0 = *(const short8*)((const char*)bufB + (rbB + kby)); \
    short8 bf1 = *(const short8*)((const char*)bufB + (rbB + 1024 + kby)); \
    _Pragma("unroll") \
    for (int mi = 0; mi < 4; ++mi) { \
        short8 af = *(const short8*)((const char*)bufA + (rbA + mi * 1024 + kby)); \
        acc[mi][0] = __builtin_amdgcn_mfma_f32_16x16x32_bf16(af, bf0, acc[mi][0], 0, 0, 0); \
        acc[mi][1] = __builtin_amdgcn_mfma_f32_16x16x32_bf16(af, bf1, acc[mi][1], 0, 0, 0); \
    } \
    __builtin_amdgcn_s_setprio(0); \
    if ((S) + 1 < nsteps) { \
        const int nxt_ = cur_ ^ 1; \
        *(short8*)((char*)lsA[nxt_] + wby) = cvt8(RA[0], RA[1]); \
        if (!same) *(short8*)((char*)lsB[nxt_] + wby) = cvt8(RB[0], RB[1]); \
        if ((S) + 3 < nsteps) { \
            const float4* p_ = (const float4*)(gA + ((S) + 3) * 32); \
            RA[0] = p_[0]; RA[1] = p_[1]; \
            if (!same) { \
                const float4* q_ = (const float4*)(gB + ((S) + 3) * 32); \
                RB[0] = q_[0]; RB[1] = q_[1]; \
            } \
        } \
    } \
    asm volatile("s_waitcnt lgkmcnt(0)" ::: "memory"); \
    __builtin_amdgcn_s_barrier(); \
}

template<bool STORE>
__global__ __launch_bounds__(512, 4)
void gram_kernel(const float* __restrict__ pred, const float* __restrict__ tgt,
                 float* __restrict__ out, float* __restrict__ norms) {
    int m, ti, tj, k0, nsteps;
    decode_bid(blockIdx.x, m, ti, tj, k0, nsteps);
    const bool same = (ti == tj);
    const float* __restrict__ x = m ? tgt : pred;

    __shared__ short lsA[2][4096];   // [128 rows][32 k] bf16, XOR-swizzled 16B slots
    __shared__ short lsB[2][4096];

    const int tid = threadIdx.x;
    const int lane = tid & 63;
    const int wid = tid >> 6;
    const int wr = wid >> 2, wc = wid & 3;   // 8 waves: 2x4 grid of 64x32 wave tiles

    // staging: one 8-float slot per thread per matrix: row = tid>>2, k-slot = tid&3
    const int srow = tid >> 2, sc8 = tid & 3;
    const float* __restrict__ gA = x + (size_t)(ti * 128 + srow) * D + k0 + sc8 * 8;
    const float* __restrict__ gB = x + (size_t)(tj * 128 + srow) * D + k0 + sc8 * 8;
    const int wby = srow * 64 + ((sc8 ^ ((srow >> 1) & 3)) << 4);  // swizzled LDS byte offset

    // fragment read offsets (swizzle-consistent: 16/64-row strides don't touch (row>>1)&3)
    const int rbA = (wr * 64 + (lane & 15)) * 64;
    const int rbB = (wc * 32 + (lane & 15)) * 64;
    const int kby = (((lane >> 4) ^ (((lane & 15) >> 1) & 3)) << 4);

    f32x4 zero = {0.f, 0.f, 0.f, 0.f};
    f32x4 acc[4][2];
#pragma unroll
    for (int mi = 0; mi < 4; ++mi) { acc[mi][0] = zero; acc[mi][1] = zero; }

    // two named prefetch register sets (static indexing only — no runtime-indexed arrays)
    float4 raX[2], rbX[2], raY[2], rbY[2];

    // prologue: step0 -> raX -> buf0; step1 -> raX; step2 -> raY   (depth-3 pipeline)
    { const float4* p = (const float4*)gA; raX[0] = p[0]; raX[1] = p[1];
      if (!same) { const float4* q = (const float4*)gB; rbX[0] = q[0]; rbX[1] = q[1]; } }
    *(short8*)((char*)lsA[0] + wby) = cvt8(raX[0], raX[1]);
    if (!same) *(short8*)((char*)lsB[0] + wby) = cvt8(rbX[0], rbX[1]);
    { const float4* p = (const float4*)(gA + 32); raX[0] = p[0]; raX[1] = p[1];
      if (!same) { const float4* q = (const float4*)(gB + 32); rbX[0] = q[0]; rbX[1] = q[1]; } }
    { const float4* p = (const float4*)(gA + 64); raY[0] = p[0]; raY[1] = p[1];
      if (!same) { const float4* q = (const float4*)(gB + 64); rbY[0] = q[0]; rbY[1] = q[1]; } }
    asm volatile("s_waitcnt lgkmcnt(0)" ::: "memory");
    __builtin_amdgcn_s_barrier();

    // nsteps is even (16 or 32): unrolled x2 so the set parity is compile-time static
    for (int sp = 0; sp < nsteps; sp += 2) {
        GRAM_STEP(sp,     raX, rbX)
        GRAM_STEP(sp + 1, raY, rbY)
    }

    if (STORE) {
        float* __restrict__ dst = out + (size_t)blockIdx.x * 16384;
#pragma unroll
        for (int mi = 0; mi < 4; ++mi)
#pragma unroll
            for (int ni = 0; ni < 2; ++ni)
#pragma unroll
                for (int r = 0; r < 4; ++r) {
                    int li = wr * 64 + mi * 16 + (lane >> 4) * 4 + r;
                    int lj = wc * 32 + ni * 16 + (lane & 15);
                    dst[li * 128 + lj] = acc[mi][ni][r];
                    // norms from diag-tile diagonals (norms buffer zeroed by memsetAsync)
                    if (same && li == lj)
                        atomicAdd(&norms[m * 1024 + ti * 128 + li], acc[mi][ni][r]);
                }
    } else {
        float* __restrict__ g = out + (size_t)m * (1024 * 1024);
#pragma unroll
        for (int mi = 0; mi < 4; ++mi)
#pragma unroll
            for (int ni = 0; ni < 2; ++ni)
#pragma unroll
                for (int r = 0; r < 4; ++r) {
                    int gi = ti * 128 + wr * 64 + mi * 16 + (lane >> 4) * 4 + r;
                    int gj = tj * 128 + wc * 32 + ni * 16 + (lane & 15);
                    atomicAdd(&g[gi * 1024 + gj], acc[mi][ni][r]);
                }
    }
}

// loss: wave = 64 consecutive j of one i (coalesced scalar gathers),
// per-block partial store, separate tiny finalize kernel (no fences, no same-addr atomics).
__global__ __launch_bounds__(256)
void loss_store_kernel(const float* __restrict__ part, const float* __restrict__ norms,
                       float* __restrict__ partial) {
    const int tid = threadIdx.x;
    const int base = blockIdx.x * 256 + tid;
    float local = 0.f;
#pragma unroll
    for (int s = 0; s < 4; ++s) {
        int lin = base + s * 262144;
        int i = lin >> 10, j = lin & 1023;
        if (j > i) {
            int ti = i >> 7, tj = j >> 7;
            int el = ((i & 127) << 7) + (j & 127);
            float gp = 0.f, gt = 0.f;
            if (ti == tj) {
#pragma unroll
                for (int c = 0; c < 8; ++c) {
                    gp += part[(size_t)bid_diag(0, ti, c) * 16384 + el];
                    gt += part[(size_t)bid_diag(1, ti, c) * 16384 + el];
                }
            } else {
                int tt = 7 * ti - (ti * (ti - 1)) / 2 + (tj - ti - 1);
#pragma unroll
                for (int c = 0; c < 16; ++c) {
                    gp += part[(size_t)bid_off(0, tt, c) * 16384 + el];
                    gt += part[(size_t)bid_off(1, tt, c) * 16384 + el];
                }
            }
            float dp = norms[i] + norms[j] - 2.f * gp;
            float dt_ = norms[1024 + i] + norms[1024 + j] - 2.f * gt;
            float c2 = sqrtf(fmaxf(dp, 0.f)) - sqrtf(fmaxf(dt_, 0.f));
            local += c2 * c2;
        }
    }
#pragma unroll
    for (int off = 32; off > 0; off >>= 1) local += __shfl_down(local, off);
    __shared__ float wsum[4];
    if ((tid & 63) == 0) wsum[tid >> 6] = local;
    __syncthreads();
    if (tid == 0) partial[blockIdx.x] = wsum[0] + wsum[1] + wsum[2] + wsum[3];
}

// fallback loss (atomic gram path): reads dense gram[2][1024][1024]
__global__ __launch_bounds__(256)
void loss_atomic_kernel(const float* __restrict__ gram, float* __restrict__ partial) {
    const float* __restrict__ gP = gram;
    const float* __restrict__ gT = gram + 1024 * 1024;
    const int tid = threadIdx.x;
    const int base = blockIdx.x * 256 + tid;
    float local = 0.f;
#pragma unroll
    for (int s = 0; s < 4; ++s) {
        int lin = base + s * 262144;
        int i = lin >> 10, j = lin & 1023;
        if (j > i) {
            float dp = gP[i * 1024 + i] + gP[j * 1024 + j] - 2.f * gP[lin];
            float dt = gT[i * 1024 + i] + gT[j * 1024 + j] - 2.f * gT[lin];
            float c = sqrtf(fmaxf(dp, 0.f)) - sqrtf(fmaxf(dt, 0.f));
            local += c * c;
        }
    }
#pragma unroll
    for (int off = 32; off > 0; off >>= 1) local += __shfl_down(local, off);
    __shared__ float wsum[4];
    if ((tid & 63) == 0) wsum[tid >> 6] = local;
    __syncthreads();
    if (tid == 0) partial[blockIdx.x] = wsum[0] + wsum[1] + wsum[2] + wsum[3];
}

__global__ __launch_bounds__(256)
void finalize_kernel(const float* __restrict__ partial, float* __restrict__ out) {
    const int tid = threadIdx.x;
    double local = 0.0;
#pragma unroll
    for (int k = 0; k < 4; ++k) local += (double)partial[tid + k * 256];
#pragma unroll
    for (int off = 32; off > 0; off >>= 1) local += __shfl_down(local, off);
    __shared__ double wsum[4];
    if ((tid & 63) == 0) wsum[tid >> 6] = local;
    __syncthreads();
    if (tid == 0) out[0] = (float)((wsum[0] + wsum[1] + wsum[2] + wsum[3]) / NPAIR);
}

extern "C" void kernel_launch(void* const* d_in, const int* in_sizes, int n_in,
                              void* d_out, int out_size, void* d_ws, size_t ws_size,
                              hipStream_t stream) {
    const float* pred = (const float*)d_in[0];
    const float* tgt  = (const float*)d_in[1];
    float* ws = (float*)d_ws;
    // layout: part[1024*16384] | norms[2048] | partial[1024]
    const size_t need = ((size_t)1024 * 16384 + 2048 + 1024) * 4;
    if (ws_size >= need) {
        float* part    = ws;
        float* norms   = ws + (size_t)1024 * 16384;
        float* partial = norms + 2048;
        hipMemsetAsync(norms, 0, 2048 * sizeof(float), stream);
        gram_kernel<true><<<1024, 512, 0, stream>>>(pred, tgt, part, norms);
        loss_store_kernel<<<1024, 256, 0, stream>>>(part, norms, partial);
        finalize_kernel<<<1, 256, 0, stream>>>(partial, (float*)d_out);
    } else {
        float* gram    = ws;                            // 2 x 1024 x 1024 f32 = 8 MB
        float* partial = ws + (size_t)2 * 1024 * 1024;
        hipMemsetAsync(gram, 0, (size_t)2 * 1024 * 1024 * sizeof(float), stream);
        gram_kernel<false><<<1024, 512, 0, stream>>>(pred, tgt, gram, nullptr);
        loss_atomic_kernel<<<1024, 256, 0, stream>>>(gram, partial);
        finalize_kernel<<<1, 256, 0, stream>>>(partial, (float*)d_out);
    }
}

// Round 9
// 54.513 us; speedup vs baseline: 1.5115x; 1.1456x over previous
//
#include <hip/hip_runtime.h>
#include <hip/hip_bf16.h>
#include <hip/hip_fp16.h>

#define D 8192
#define NPAIR 523776.0

typedef short short8 __attribute__((ext_vector_type(8)));
typedef float f32x4 __attribute__((ext_vector_type(4)));

__device__ __forceinline__ short8 cvt8(const float4 a, const float4 b) {
    union { short8 s; __hip_bfloat162 h[4]; } u;
    u.h[0] = __float22bfloat162_rn(make_float2(a.x, a.y));
    u.h[1] = __float22bfloat162_rn(make_float2(a.z, a.w));
    u.h[2] = __float22bfloat162_rn(make_float2(b.x, b.y));
    u.h[3] = __float22bfloat162_rn(make_float2(b.z, b.w));
    return u.s;
}

// 1024 blocks, bid = x(0..7, XCD slot) + 8*s.  m = x>>2, xr = x&3.
// DIAG FIRST (2x steps -> start at t=0 to kill the tail):
//   s < 16 : diag tiles. dt = s&7, c = (s>>3)*4 + xr (8 chunks of K=1024, 32 steps @ BK=32)
//   s >= 16: off-diag.  sp = s-16: c = (sp/28)*4 + xr (16 chunks of K=512, 16 steps @ BK=32)
__device__ __forceinline__ void decode_bid(int bid, int& m, int& ti, int& tj, int& k0, int& nsteps) {
    int x = bid & 7, s = bid >> 3;
    m = x >> 2;
    int xr = x & 3;
    if (s < 16) {
        ti = tj = s & 7;
        int c = ((s >> 3) << 2) + xr;
        k0 = c * 1024; nsteps = 32;
    } else {
        int sp = s - 16;
        int c = (sp / 28) * 4 + xr;
        int tt = sp % 28;
        int a = 0;
        while (tt >= 7 - a) { tt -= 7 - a; ++a; }
        ti = a; tj = a + 1 + tt;
        k0 = c * 512; nsteps = 16;
    }
}
__device__ __forceinline__ int bid_off(int m, int tt, int c) {
    return (m * 4 + (c & 3)) + ((16 + (c >> 2) * 28 + tt) << 3);
}
__device__ __forceinline__ int bid_diag(int m, int dt, int c) {
    return (m * 4 + (c & 3)) + ((((c >> 2) << 3) + dt) << 3);
}

// one pipeline step: MFMA on lsX[S&1]; write staged regs (data for step S+1) to
// lsX[(S&1)^1]; issue loads for step S+3 into the same (now free) register set.
#define GRAM_STEP(S, RA, RB) { \
    const int cur_ = (S) & 1; \
    const short* __restrict__ bufA = lsA[cur_]; \
    const short* __restrict__ bufB = same ? lsA[cur_] : lsB[cur_]; \
    __builtin_amdgcn_s_setprio(1); \
    short8 bf0 = *(const short8*)((const char*)bufB + (rbB + kby)); \
    short8 bf1 = *(const short8*)((const char*)bufB + (rbB + 1024 + kby)); \
    _Pragma("unroll") \
    for (int mi = 0; mi < 4; ++mi) { \
        short8 af = *(const short8*)((const char*)bufA + (rbA + mi * 1024 + kby)); \
        acc[mi][0] = __builtin_amdgcn_mfma_f32_16x16x32_bf16(af, bf0, acc[mi][0], 0, 0, 0); \
        acc[mi][1] = __builtin_amdgcn_mfma_f32_16x16x32_bf16(af, bf1, acc[mi][1], 0, 0, 0); \
    } \
    __builtin_amdgcn_s_setprio(0); \
    if ((S) + 1 < nsteps) { \
        const int nxt_ = cur_ ^ 1; \
        *(short8*)((char*)lsA[nxt_] + wby) = cvt8(RA[0], RA[1]); \
        if (!same) *(short8*)((char*)lsB[nxt_] + wby) = cvt8(RB[0], RB[1]); \
        if ((S) + 3 < nsteps) { \
            const float4* p_ = (const float4*)(gA + ((S) + 3) * 32); \
            RA[0] = p_[0]; RA[1] = p_[1]; \
            if (!same) { \
                const float4* q_ = (const float4*)(gB + ((S) + 3) * 32); \
                RB[0] = q_[0]; RB[1] = q_[1]; \
            } \
        } \
    } \
    asm volatile("s_waitcnt lgkmcnt(0)" ::: "memory"); \
    __builtin_amdgcn_s_barrier(); \
}

template<bool STORE>
__global__ __launch_bounds__(512, 4)
void gram_kernel(const float* __restrict__ pred, const float* __restrict__ tgt,
                 void* __restrict__ outv, float* __restrict__ norms) {
    int m, ti, tj, k0, nsteps;
    decode_bid(blockIdx.x, m, ti, tj, k0, nsteps);
    const bool same = (ti == tj);
    const float* __restrict__ x = m ? tgt : pred;

    __shared__ short lsA[2][4096];   // [128 rows][32 k] bf16, XOR-swizzled 16B slots
    __shared__ short lsB[2][4096];

    const int tid = threadIdx.x;
    const int lane = tid & 63;
    const int wid = tid >> 6;
    const int wr = wid >> 2, wc = wid & 3;   // 8 waves: 2x4 grid of 64x32 wave tiles

    // staging: one 8-float slot per thread per matrix: row = tid>>2, k-slot = tid&3
    const int srow = tid >> 2, sc8 = tid & 3;
    const float* __restrict__ gA = x + (size_t)(ti * 128 + srow) * D + k0 + sc8 * 8;
    const float* __restrict__ gB = x + (size_t)(tj * 128 + srow) * D + k0 + sc8 * 8;
    const int wby = srow * 64 + ((sc8 ^ ((srow >> 1) & 3)) << 4);  // swizzled LDS byte offset

    // fragment read offsets (swizzle-consistent: 16/64-row strides don't touch (row>>1)&3)
    const int rbA = (wr * 64 + (lane & 15)) * 64;
    const int rbB = (wc * 32 + (lane & 15)) * 64;
    const int kby = (((lane >> 4) ^ (((lane & 15) >> 1) & 3)) << 4);

    f32x4 zero = {0.f, 0.f, 0.f, 0.f};
    f32x4 acc[4][2];
#pragma unroll
    for (int mi = 0; mi < 4; ++mi) { acc[mi][0] = zero; acc[mi][1] = zero; }

    // two named prefetch register sets (static indexing only — no runtime-indexed arrays)
    float4 raX[2], rbX[2], raY[2], rbY[2];

    // prologue: step0 -> raX -> buf0; step1 -> raX; step2 -> raY   (depth-3 pipeline)
    { const float4* p = (const float4*)gA; raX[0] = p[0]; raX[1] = p[1];
      if (!same) { const float4* q = (const float4*)gB; rbX[0] = q[0]; rbX[1] = q[1]; } }
    *(short8*)((char*)lsA[0] + wby) = cvt8(raX[0], raX[1]);
    if (!same) *(short8*)((char*)lsB[0] + wby) = cvt8(rbX[0], rbX[1]);
    { const float4* p = (const float4*)(gA + 32); raX[0] = p[0]; raX[1] = p[1];
      if (!same) { const float4* q = (const float4*)(gB + 32); rbX[0] = q[0]; rbX[1] = q[1]; } }
    { const float4* p = (const float4*)(gA + 64); raY[0] = p[0]; raY[1] = p[1];
      if (!same) { const float4* q = (const float4*)(gB + 64); rbY[0] = q[0]; rbY[1] = q[1]; } }
    asm volatile("s_waitcnt lgkmcnt(0)" ::: "memory");
    __builtin_amdgcn_s_barrier();

    // nsteps is even (16 or 32): unrolled x2 so the set parity is compile-time static
    for (int sp = 0; sp < nsteps; sp += 2) {
        GRAM_STEP(sp,     raX, rbX)
        GRAM_STEP(sp + 1, raY, rbY)
    }

    if (STORE) {
        // fp16 partials: halves the partial write (gram) + re-read (loss) HBM traffic.
        // |chunk partial| <~ 160, fp16 rel err 2^-12 -> scalar loss err ~1e-3 << 4e-2 thr.
        __half* __restrict__ dst = (__half*)outv + (size_t)blockIdx.x * 16384;
#pragma unroll
        for (int mi = 0; mi < 4; ++mi)
#pragma unroll
            for (int ni = 0; ni < 2; ++ni)
#pragma unroll
                for (int r = 0; r < 4; ++r) {
                    int li = wr * 64 + mi * 16 + (lane >> 4) * 4 + r;
                    int lj = wc * 32 + ni * 16 + (lane & 15);
                    dst[li * 128 + lj] = __float2half_rn(acc[mi][ni][r]);
                    // norms from diag-tile diagonals (fp32; buffer zeroed by memsetAsync)
                    if (same && li == lj)
                        atomicAdd(&norms[m * 1024 + ti * 128 + li], acc[mi][ni][r]);
                }
    } else {
        float* __restrict__ g = (float*)outv + (size_t)m * (1024 * 1024);
#pragma unroll
        for (int mi = 0; mi < 4; ++mi)
#pragma unroll
            for (int ni = 0; ni < 2; ++ni)
#pragma unroll
                for (int r = 0; r < 4; ++r) {
                    int gi = ti * 128 + wr * 64 + mi * 16 + (lane >> 4) * 4 + r;
                    int gj = tj * 128 + wc * 32 + ni * 16 + (lane & 15);
                    atomicAdd(&g[gi * 1024 + gj], acc[mi][ni][r]);
                }
    }
}

// loss: wave = 64 consecutive j of one i (coalesced fp16 gathers),
// per-block partial store, separate tiny finalize kernel (no fences, no same-addr atomics).
__global__ __launch_bounds__(256)
void loss_store_kernel(const __half* __restrict__ part, const float* __restrict__ norms,
                       float* __restrict__ partial) {
    const int tid = threadIdx.x;
    const int base = blockIdx.x * 256 + tid;
    float local = 0.f;
#pragma unroll
    for (int s = 0; s < 4; ++s) {
        int lin = base + s * 262144;
        int i = lin >> 10, j = lin & 1023;
        if (j > i) {
            int ti = i >> 7, tj = j >> 7;
            int el = ((i & 127) << 7) + (j & 127);
            float gp = 0.f, gt = 0.f;
            if (ti == tj) {
#pragma unroll
                for (int c = 0; c < 8; ++c) {
                    gp += __half2float(part[(size_t)bid_diag(0, ti, c) * 16384 + el]);
                    gt += __half2float(part[(size_t)bid_diag(1, ti, c) * 16384 + el]);
                }
            } else {
                int tt = 7 * ti - (ti * (ti - 1)) / 2 + (tj - ti - 1);
#pragma unroll
                for (int c = 0; c < 16; ++c) {
                    gp += __half2float(part[(size_t)bid_off(0, tt, c) * 16384 + el]);
                    gt += __half2float(part[(size_t)bid_off(1, tt, c) * 16384 + el]);
                }
            }
            float dp = norms[i] + norms[j] - 2.f * gp;
            float dt_ = norms[1024 + i] + norms[1024 + j] - 2.f * gt;
            float c2 = sqrtf(fmaxf(dp, 0.f)) - sqrtf(fmaxf(dt_, 0.f));
            local += c2 * c2;
        }
    }
#pragma unroll
    for (int off = 32; off > 0; off >>= 1) local += __shfl_down(local, off);
    __shared__ float wsum[4];
    if ((tid & 63) == 0) wsum[tid >> 6] = local;
    __syncthreads();
    if (tid == 0) partial[blockIdx.x] = wsum[0] + wsum[1] + wsum[2] + wsum[3];
}

// fallback loss (atomic gram path): reads dense gram[2][1024][1024]
__global__ __launch_bounds__(256)
void loss_atomic_kernel(const float* __restrict__ gram, float* __restrict__ partial) {
    const float* __restrict__ gP = gram;
    const float* __restrict__ gT = gram + 1024 * 1024;
    const int tid = threadIdx.x;
    const int base = blockIdx.x * 256 + tid;
    float local = 0.f;
#pragma unroll
    for (int s = 0; s < 4; ++s) {
        int lin = base + s * 262144;
        int i = lin >> 10, j = lin & 1023;
        if (j > i) {
            float dp = gP[i * 1024 + i] + gP[j * 1024 + j] - 2.f * gP[lin];
            float dt = gT[i * 1024 + i] + gT[j * 1024 + j] - 2.f * gT[lin];
            float c = sqrtf(fmaxf(dp, 0.f)) - sqrtf(fmaxf(dt, 0.f));
            local += c * c;
        }
    }
#pragma unroll
    for (int off = 32; off > 0; off >>= 1) local += __shfl_down(local, off);
    __shared__ float wsum[4];
    if ((tid & 63) == 0) wsum[tid >> 6] = local;
    __syncthreads();
    if (tid == 0) partial[blockIdx.x] = wsum[0] + wsum[1] + wsum[2] + wsum[3];
}

__global__ __launch_bounds__(256)
void finalize_kernel(const float* __restrict__ partial, float* __restrict__ out) {
    const int tid = threadIdx.x;
    double local = 0.0;
#pragma unroll
    for (int k = 0; k < 4; ++k) local += (double)partial[tid + k * 256];
#pragma unroll
    for (int off = 32; off > 0; off >>= 1) local += __shfl_down(local, off);
    __shared__ double wsum[4];
    if ((tid & 63) == 0) wsum[tid >> 6] = local;
    __syncthreads();
    if (tid == 0) out[0] = (float)((wsum[0] + wsum[1] + wsum[2] + wsum[3]) / NPAIR);
}

extern "C" void kernel_launch(void* const* d_in, const int* in_sizes, int n_in,
                              void* d_out, int out_size, void* d_ws, size_t ws_size,
                              hipStream_t stream) {
    const float* pred = (const float*)d_in[0];
    const float* tgt  = (const float*)d_in[1];
    // layout: part fp16 [1024*16384] (33.5 MB) | norms f32 [2048] | partial f32 [1024]
    const size_t part_bytes = (size_t)1024 * 16384 * sizeof(__half);
    const size_t need = part_bytes + (2048 + 1024) * sizeof(float);
    if (ws_size >= need) {
        __half* part   = (__half*)d_ws;
        float* norms   = (float*)((char*)d_ws + part_bytes);
        float* partial = norms + 2048;
        hipMemsetAsync(norms, 0, 2048 * sizeof(float), stream);
        gram_kernel<true><<<1024, 512, 0, stream>>>(pred, tgt, (void*)part, norms);
        loss_store_kernel<<<1024, 256, 0, stream>>>(part, norms, partial);
        finalize_kernel<<<1, 256, 0, stream>>>(partial, (float*)d_out);
    } else {
        float* gram    = (float*)d_ws;                  // 2 x 1024 x 1024 f32 = 8 MB
        float* partial = (float*)d_ws + (size_t)2 * 1024 * 1024;
        hipMemsetAsync(gram, 0, (size_t)2 * 1024 * 1024 * sizeof(float), stream);
        gram_kernel<false><<<1024, 512, 0, stream>>>(pred, tgt, (void*)gram, nullptr);
        loss_atomic_kernel<<<1024, 256, 0, stream>>>(gram, partial);
        finalize_kernel<<<1, 256, 0, stream>>>(partial, (float*)d_out);
    }
}